// Round 7
// baseline (564.104 us; speedup 1.0000x reference)
//
#include <hip/hip_runtime.h>
#include <hip/hip_fp16.h>

// Problem constants (b=8, s=4096, EMBED=1024, HEADS=16, HEAD_DIM=64)
#define NTOK 32768
#define NE   1024

typedef _Float16 half_t;
typedef _Float16 f16x8 __attribute__((ext_vector_type(8)));
typedef _Float16 f16x4 __attribute__((ext_vector_type(4)));
typedef float    f32x4 __attribute__((ext_vector_type(4)));

typedef __attribute__((address_space(1))) const unsigned int guint;
typedef __attribute__((address_space(3))) unsigned int luint;

__device__ __forceinline__ void async16(const void* g, void* l) {
    __builtin_amdgcn_global_load_lds((guint*)g, (luint*)l, 16, 0, 0);
}

// ---------------------------------------------------------------- convert
__global__ __launch_bounds__(256) void cvt_f32_f16(const float* __restrict__ s,
                                                   half_t* __restrict__ d, int n) {
    int i = (blockIdx.x * 256 + threadIdx.x) * 8;
    if (i >= n) return;
    float4 a = *(const float4*)(s + i);
    float4 b = *(const float4*)(s + i + 4);
    f16x8 h = {(_Float16)a.x, (_Float16)a.y, (_Float16)a.z, (_Float16)a.w,
               (_Float16)b.x, (_Float16)b.y, (_Float16)b.z, (_Float16)b.w};
    *(f16x8*)(d + i) = h;
}

// all four 1024x1024 weights in one launch (y = matrix index)
__global__ __launch_bounds__(256) void cvt4_f32_f16(const float* __restrict__ s0,
                                                    const float* __restrict__ s1,
                                                    const float* __restrict__ s2,
                                                    const float* __restrict__ s3,
                                                    half_t* __restrict__ d) {
    const float* srcs[4] = {s0, s1, s2, s3};
    const float* s = srcs[blockIdx.y];
    int i = (blockIdx.x * 256 + threadIdx.x) * 8;
    float4 a = *(const float4*)(s + i);
    float4 b = *(const float4*)(s + i + 4);
    f16x8 h = {(_Float16)a.x, (_Float16)a.y, (_Float16)a.z, (_Float16)a.w,
               (_Float16)b.x, (_Float16)b.y, (_Float16)b.z, (_Float16)b.w};
    *(f16x8*)(d + (size_t)blockIdx.y * (NE * NE) + i) = h;
}

// ---------------------------------------------------------------- GEMM C = A * B^T
// R10 GEMM = R9/R5 verbatim (measured: QKV 213 us, MfmaUtil 43%, FETCH 189 MB,
// WRITE 196.6 MB). Ablation history proved every piece load-bearing:
//  - launch-per-round (not persistent): R8 persistent -> FETCH 822 MB, 3.2x.
//  - B staged in LDS (not global->reg): R7 -> MfmaUtil 28%, gather-bound.
//  - 3-phase stage->retire depth sufficient; deeper neutral (R6).
//  - HK-ordered phases (reads before barrier, MFMA after) + LDS-coalesced
//    epilogue: R5's +43 us over R4.

#define WAITV(N) asm volatile("s_waitcnt vmcnt(" #N ")" ::: "memory")
#define BARRIER()                              \
    do {                                       \
        asm volatile("" ::: "memory");         \
        __builtin_amdgcn_s_barrier();          \
        asm volatile("" ::: "memory");         \
    } while (0)

#define ASC(b, c) (Asm + ((b) * 2 + (c)) * 8192)
#define BSC(b, c) (Bsm + ((b) * 2 + (c)) * 8192)

// stage one A-chunk q of K-tile at col k0 into LDS chunk dst (16 KiB).
// phys row = l*64 + rr  <->  logical A row = l*128 + q*64 + rr
#define STAGE_A(dst, q, k0)                                                   \
    do {                                                                      \
        _Pragma("unroll") for (int l = 0; l < 2; ++l)                         \
            async16(Ag + (size_t)(l * 128 + (q) * 64 + rr) * K + (k0) + cc,   \
                    (char*)(dst) + l * 8192 + w * 1024);                      \
    } while (0)

// stage one B-chunk r: phys row = l*64 + rr  <->  logical B col-row =
// (l*2 + wb)*64 + r*32 + (rr&31)
#define STAGE_B(dst, r, k0)                                                   \
    do {                                                                      \
        _Pragma("unroll") for (int l = 0; l < 2; ++l)                         \
            async16(Bg + (size_t)((l * 2 + wb) * 64 + (r) * 32 + (rr & 31)) * K + \
                        (k0) + cc,                                            \
                    (char*)(dst) + l * 8192 + w * 1024);                      \
    } while (0)

// read the 8 A frags (4 mt x 2 kk) of chunk q (buffer b) for this wave
#define READ_A(dstf, b, q)                                                    \
    do {                                                                      \
        _Pragma("unroll") for (int i = 0; i < 4; ++i)                         \
        _Pragma("unroll") for (int x = 0; x < 2; ++x)                         \
            dstf[i][x] = *(const f16x8*)&ASC(b, q)[(wr * 64 + i * 16 + l16) * 64 + \
                                                   (((x * 4 + quad) ^ sw) * 8)]; \
    } while (0)

// read the 4 B frags (2 nt x 2 kk) of chunk r (buffer b) for this wave
#define READ_B(dstf, b, r)                                                    \
    do {                                                                      \
        _Pragma("unroll") for (int i2 = 0; i2 < 2; ++i2)                      \
        _Pragma("unroll") for (int x = 0; x < 2; ++x)                         \
            dstf[i2][x] = *(const f16x8*)&BSC(b, r)[(wc * 32 + i2 * 16 + l16) * 64 + \
                                                    (((x * 4 + quad) ^ sw) * 8)]; \
    } while (0)

// one quadrant: 16 MFMAs into acc[QA*4+i][RB*2+jj]
#define MMA(af, bf, QA, RB)                                                   \
    do {                                                                      \
        __builtin_amdgcn_s_setprio(1);                                        \
        _Pragma("unroll") for (int i = 0; i < 4; ++i)                         \
        _Pragma("unroll") for (int jj = 0; jj < 2; ++jj)                      \
        _Pragma("unroll") for (int x = 0; x < 2; ++x)                         \
            acc[(QA) * 4 + i][(RB) * 2 + jj] =                                \
                __builtin_amdgcn_mfma_f32_16x16x32_f16(                       \
                    af[i][x], bf[jj][x], acc[(QA) * 4 + i][(RB) * 2 + jj], 0, 0, 0); \
        __builtin_amdgcn_s_setprio(0);                                        \
    } while (0)

template <bool QKV>
__global__ __launch_bounds__(512, 2) void gemm_bt(const half_t* __restrict__ A,
                                                  const half_t* __restrict__ Bbase,
                                                  void* __restrict__ Cout,
                                                  const float* __restrict__ theta) {
    constexpr int K  = 1024;
    constexpr int NT = 16;             // K / 64 K-tiles
    constexpr int J  = QKV ? 12 : 4;   // (z, xt) blocks per m-tile
    __shared__ alignas(16) half_t smem[65536];  // 128 KiB
    half_t* Asm = smem;
    half_t* Bsm = smem + 32768;

    const int id    = blockIdx.x;
    const int xcd   = id & 7;
    const int slot  = id >> 3;
    const int ygrp  = slot / J;
    const int j     = slot - ygrp * J;
    const int mtile = ygrp * 8 + xcd;
    const int zsl   = QKV ? (j >> 2) : 0;
    const int xt    = QKV ? (j & 3) : j;

    const int tid  = threadIdx.x;
    const int w    = tid >> 6;
    const int lane = tid & 63;
    const int quad = lane >> 4;
    const int l16  = lane & 15;
    const int sw   = l16 & 7;
    const int wr   = w >> 2, wc = w & 3;  // 2 x 4 waves, each 128x64 of C
    const size_t m0 = (size_t)mtile * 256;
    const int    n0 = xt * 256;

    const half_t* Ag = A + m0 * K;
    const half_t* Bg = Bbase + (size_t)zsl * (size_t)(NE * NE) + (size_t)n0 * K;

    const int rr = tid >> 3;                     // staging row within 64-group
    const int cc = ((tid & 7) ^ (rr & 7)) * 8;   // XOR-pre-swizzled source col
    const int wb = tid >> 8;                     // B col-row bit

    f32x4 acc[8][4];
#pragma unroll
    for (int i = 0; i < 8; ++i)
#pragma unroll
        for (int jj = 0; jj < 4; ++jj) acc[i][jj] = (f32x4){0.f, 0.f, 0.f, 0.f};

    // prologue: 5 chunks issued; retire first two; read first quadrant frags
    STAGE_A(ASC(0, 0), 0, 0);    // A0(0)
    STAGE_B(BSC(0, 0), 0, 0);    // B0(0)
    STAGE_B(BSC(0, 1), 1, 0);    // B1(0)
    STAGE_A(ASC(0, 1), 1, 0);    // A1(0)
    STAGE_A(ASC(1, 0), 0, 64);   // A0(1)
    WAITV(6);                    // retire A0(0), B0(0)
    BARRIER();

    f16x8 aF0[4][2], aF1[4][2], bF0[2][2], bF1[2][2];
    READ_A(aF0, 0, 0);
    READ_B(bF0, 0, 0);
    // invariant before P0(t): outstanding = {B1(t), A1(t), A0(t+1)} = 6 loads

    for (int t = 0; t < NT - 1; ++t) {
        const int cur = t & 1, nxt = cur ^ 1;
        const int kn = (t + 1) * 64;
        // P0: MFMA (A0,B0); stage B0(t+1); read bF1 for P1
        WAITV(4);                 // retire B1(t)
        BARRIER();
        STAGE_B(BSC(nxt, 0), 0, kn);
        MMA(aF0, bF0, 0, 0);
        READ_B(bF1, cur, 1);
        BARRIER();
        // P1: MFMA (A0,B1); stage B1(t+1); read aF1 for P2
        WAITV(4);                 // retire A1(t)
        BARRIER();
        STAGE_B(BSC(nxt, 1), 1, kn);
        MMA(aF0, bF1, 0, 1);
        READ_A(aF1, cur, 1);
        BARRIER();
        // P2: MFMA (A1,B1); stage A1(t+1); no read (aF1,bF0 live)
        WAITV(4);                 // retire A0(t+1) (read at P3 end)
        BARRIER();
        STAGE_A(ASC(nxt, 1), 1, kn);
        MMA(aF1, bF1, 1, 1);
        BARRIER();
        // P3: MFMA (A1,B0); stage A0(t+2); read aF0,bF0 of tile t+1
        WAITV(4);                 // retire B0(t+1)
        BARRIER();
        if (t + 2 < NT) STAGE_A(ASC(cur, 0), 0, kn + 64);
        MMA(aF1, bF0, 1, 0);
        READ_A(aF0, nxt, 0);
        READ_B(bF0, nxt, 0);
        BARRIER();
    }
    // t = NT-1 peeled: outstanding = {B1(15), A1(15)} = 4 loads
    {
        WAITV(2);                 // retire B1(15)
        BARRIER();
        MMA(aF0, bF0, 0, 0);
        READ_B(bF1, 1, 1);
        BARRIER();
        WAITV(0);                 // retire A1(15)
        BARRIER();
        MMA(aF0, bF1, 0, 1);
        READ_A(aF1, 1, 1);
        BARRIER();
        MMA(aF1, bF1, 1, 1);
        MMA(aF1, bF0, 1, 0);
    }
    __syncthreads();  // LDS now dead -> reuse for coalesced C staging

    // C/D layout: col = lane&15, row = quad*4 + reg  [m89]
    if (QKV) {
        // stage cos(acc+theta) as f16 [256][256] in LDS with bank-XOR
        half_t* Cl = smem;
#pragma unroll
        for (int nt = 0; nt < 4; ++nt) {
            const int col = wc * 64 + nt * 16 + l16;
            const float th = theta[col & 63];
#pragma unroll
            for (int mt = 0; mt < 8; ++mt) {
                const int rowb = wr * 128 + mt * 16 + quad * 4;
#pragma unroll
                for (int r = 0; r < 4; ++r) {
                    const int row = rowb + r;
                    Cl[row * 256 + (col ^ (((row >> 2) & 3) << 4))] =
                        (half_t)__cosf(acc[mt][nt][r] + th);
                }
            }
        }
        __syncthreads();
        half_t* Cg = (half_t*)Cout + (size_t)zsl * ((size_t)NTOK * NE);
#pragma unroll
        for (int it = 0; it < 16; ++it) {
            const int row = it * 16 + (tid >> 5);
            const int seg = tid & 31;
            f16x8 vv = *(const f16x8*)&Cl[row * 256 +
                                          ((seg * 8) ^ (((row >> 2) & 3) << 4))];
            *(f16x8*)&Cg[(m0 + row) * NE + n0 + seg * 8] = vv;  // 512 B / 32 lanes
        }
    } else {
        // f32 out: two 128-row sweeps through LDS [128][256] f32
        float* ClF = (float*)smem;
        float* Cg  = (float*)Cout;
#pragma unroll
        for (int s = 0; s < 2; ++s) {
            if (wr == s) {
#pragma unroll
                for (int nt = 0; nt < 4; ++nt) {
                    const int col = wc * 64 + nt * 16 + l16;
#pragma unroll
                    for (int mt = 0; mt < 8; ++mt) {
                        const int rowb = mt * 16 + quad * 4;
#pragma unroll
                        for (int r = 0; r < 4; ++r) {
                            const int row = rowb + r;
                            ClF[row * 256 + (col ^ (((row >> 2) & 1) << 4))] =
                                acc[mt][nt][r];
                        }
                    }
                }
            }
            __syncthreads();
#pragma unroll
            for (int it = 0; it < 16; ++it) {
                const int row = it * 8 + (tid >> 6);
                const int seg = tid & 63;
                f32x4 vv = *(const f32x4*)&ClF[row * 256 +
                                               ((seg * 4) ^ (((row >> 2) & 1) << 4))];
                *(f32x4*)&Cg[(m0 + s * 128 + row) * NE + n0 + seg * 4] = vv;
            }
            __syncthreads();
        }
    }
}

// ---------------------------------------------------------------- MFMA attention
// R10: same verified MFMA layouts as before, but all scalar I/O vectorized:
//  - v staged ROW-major vR[16][72] with 2x f16x8 LDS writes (was 32 scalar
//    b16 writes into a transposed layout). Pad 72 keeps 16B alignment and
//    <=2-way bank aliasing (free).
//  - PV B-frag: bv[q] = vR[quad*4+q][c*16+l16] — same element mapping as the
//    old vT read (m120-verified), now 16 conflict-spread scalar LDS reads.
//  - output bounces through the (dead) vR region and stores as 2 coalesced
//    f16x8 per lane (2 KB contiguous per wave; was 16 scalar 2B stores).
//  - NO __syncthreads: vR/Pl are [w]-indexed wave-private; within-wave DS
//    ordering + lgkmcnt suffices. Defensive lgkmcnt(0)+sched_barrier(0) at
//    the vR read->overwrite WAR point (rule #18).
__global__ __launch_bounds__(512) void attn_kernel(const half_t* __restrict__ q,
                                                   const half_t* __restrict__ k,
                                                   const half_t* __restrict__ v,
                                                   half_t* __restrict__ out) {
    __shared__ alignas(16) half_t vR[8][16][72];  // [wave][head][d], pad->72
    __shared__ alignas(16) half_t Pl[8][16][20];  // [wave][i][j],   pad->20
    const int tid  = threadIdx.x;
    const int w    = tid >> 6;
    const int lane = tid & 63;
    const int quad = lane >> 4;
    const int l16  = lane & 15;
    const size_t base = ((size_t)blockIdx.x * 8 + w) * 1024;

    // stage v row-major, vectorized: lane covers head h=lane>>2, d0=(lane&3)*16
    {
        const int h = lane >> 2, d0 = (lane & 3) * 16;
        f16x8 va = *(const f16x8*)(v + base + h * 64 + d0);
        f16x8 vb = *(const f16x8*)(v + base + h * 64 + d0 + 8);
        *(f16x8*)&vR[w][h][d0]     = va;
        *(f16x8*)&vR[w][h][d0 + 8] = vb;
    }

    // scores: frags straight from global (no LDS)
    f16x8 aq0 = *(const f16x8*)(q + base + l16 * 64 + quad * 8);
    f16x8 aq1 = *(const f16x8*)(q + base + l16 * 64 + 32 + quad * 8);
    f16x8 bk0 = *(const f16x8*)(k + base + l16 * 64 + quad * 8);
    f16x8 bk1 = *(const f16x8*)(k + base + l16 * 64 + 32 + quad * 8);
    f32x4 S = __builtin_amdgcn_mfma_f32_16x16x32_f16(aq0, bk0, (f32x4){0.f,0.f,0.f,0.f}, 0, 0, 0);
    S = __builtin_amdgcn_mfma_f32_16x16x32_f16(aq1, bk1, S, 0, 0, 0);

    // softmax over cols (l16) per row (quad*4+r); write P f16 to LDS
#pragma unroll
    for (int r = 0; r < 4; ++r) {
        float s = S[r] * 0.125f;  // 1/sqrt(64)
        float mx = s;
#pragma unroll
        for (int o = 8; o; o >>= 1) mx = fmaxf(mx, __shfl_xor(mx, o));
        float e = __expf(s - mx);
        float sum = e;
#pragma unroll
        for (int o = 8; o; o >>= 1) sum += __shfl_xor(sum, o);
        Pl[w][quad * 4 + r][l16] = (half_t)(e / sum);
    }
    // no barrier: vR/Pl are wave-private; DS ops of a wave complete in order.

    // PV: A = P [m=i][k=j], B[k=j][n=d] read per-element from row-major vR
    f16x4 ap = *(const f16x4*)&Pl[w][l16][quad * 4];
    float Of[16];
#pragma unroll
    for (int c = 0; c < 4; ++c) {
        f16x4 bv;
#pragma unroll
        for (int qi = 0; qi < 4; ++qi)
            bv[qi] = vR[w][quad * 4 + qi][c * 16 + l16];
        f32x4 O = __builtin_amdgcn_mfma_f32_16x16x16f16(ap, bv, (f32x4){0.f,0.f,0.f,0.f}, 0, 0, 0);
#pragma unroll
        for (int r = 0; r < 4; ++r) Of[c * 4 + r] = O[r];
    }

    // WAR: all vR reads complete before overwrite (rule #18 fencing)
    asm volatile("s_waitcnt lgkmcnt(0)" ::: "memory");
    __builtin_amdgcn_sched_barrier(0);

    // O -> LDS bounce (reuse vR region: [head i][d]), then coalesced stores
#pragma unroll
    for (int c = 0; c < 4; ++c)
#pragma unroll
        for (int r = 0; r < 4; ++r)
            vR[w][quad * 4 + r][c * 16 + l16] = (half_t)Of[c * 4 + r];

    asm volatile("s_waitcnt lgkmcnt(0)" ::: "memory");
    __builtin_amdgcn_sched_barrier(0);
    {
        const int rw = lane >> 2, d0 = (lane & 3) * 16;
        f16x8 oa = *(const f16x8*)&vR[w][rw][d0];
        f16x8 ob = *(const f16x8*)&vR[w][rw][d0 + 8];
        *(f16x8*)(out + base + rw * 64 + d0)     = oa;
        *(f16x8*)(out + base + rw * 64 + d0 + 8) = ob;
    }
}

// ---------------------------------------------------------------- launch
extern "C" void kernel_launch(void* const* d_in, const int* in_sizes, int n_in,
                              void* d_out, int out_size, void* d_ws, size_t ws_size,
                              hipStream_t stream) {
    // setup_inputs order: x, Wk, Wq, Wv, Wo, theta
    const float* x     = (const float*)d_in[0];
    const float* Wk    = (const float*)d_in[1];
    const float* Wq    = (const float*)d_in[2];
    const float* Wv    = (const float*)d_in[3];
    const float* Wo    = (const float*)d_in[4];
    const float* theta = (const float*)d_in[5];

    char* ws = (char*)d_ws;
    half_t* xh  = (half_t*)ws;                           // 64 MB (reused for attn_out)
    half_t* wh  = (half_t*)(ws + (size_t)(64 << 20));    // 8 MB: Wq,Wk,Wv,Wo f16
    half_t* qkv = (half_t*)(ws + (size_t)(72 << 20));    // 192 MB: q_q,k_q,v_q f16

    cvt_f32_f16<<<NTOK * NE / 2048, 256, 0, stream>>>(x, xh, NTOK * NE);
    cvt4_f32_f16<<<dim3(NE * NE / 2048, 4), 256, 0, stream>>>(Wq, Wk, Wv, Wo, wh);

    // q,k,v projections + cos(.+theta): 8 xcd * 16 ygrp * 12 (z,x); 256x256 tiles
    gemm_bt<true><<<1536, 512, 0, stream>>>(xh, wh, qkv, theta);

    // per-token attention over heads (8 tokens/block)
    attn_kernel<<<NTOK / 8, 512, 0, stream>>>(qkv, qkv + (size_t)NTOK * NE,
                                              qkv + 2 * (size_t)NTOK * NE, xh);

    // out = attn_out @ Wo^T: 8 xcd * 16 ygrp * 4 xt
    gemm_bt<false><<<512, 512, 0, stream>>>(xh, wh + 3 * NE * NE, d_out, nullptr);
}

// Round 8
// 550.257 us; speedup vs baseline: 1.0252x; 1.0252x over previous
//
#include <hip/hip_runtime.h>
#include <hip/hip_fp16.h>

// Problem constants (b=8, s=4096, EMBED=1024, HEADS=16, HEAD_DIM=64)
#define NTOK 32768
#define NE   1024

typedef _Float16 half_t;
typedef _Float16 f16x8 __attribute__((ext_vector_type(8)));
typedef _Float16 f16x4 __attribute__((ext_vector_type(4)));
typedef float    f32x4 __attribute__((ext_vector_type(4)));

typedef __attribute__((address_space(1))) const unsigned int guint;
typedef __attribute__((address_space(3))) unsigned int luint;

__device__ __forceinline__ void async16(const void* g, void* l) {
    __builtin_amdgcn_global_load_lds((guint*)g, (luint*)l, 16, 0, 0);
}

// ---------------------------------------------------------------- convert
// one launch for x (16384 blocks) + 4 weight matrices (512 blocks each)
__global__ __launch_bounds__(256) void cvt_all(const float* __restrict__ x,
                                               const float* __restrict__ w0,
                                               const float* __restrict__ w1,
                                               const float* __restrict__ w2,
                                               const float* __restrict__ w3,
                                               half_t* __restrict__ dx,
                                               half_t* __restrict__ dw) {
    const int id = blockIdx.x;
    const float* s;
    half_t* d;
    int i;
    if (id < 16384) {
        s = x; d = dx;
        i = (id * 256 + threadIdx.x) * 8;
    } else {
        const int m = (id - 16384) >> 9;          // weight index 0..3
        const float* ws[4] = {w0, w1, w2, w3};
        s = ws[m];
        d = dw + (size_t)m * (NE * NE);
        i = (((id - 16384) & 511) * 256 + threadIdx.x) * 8;
    }
    float4 a = *(const float4*)(s + i);
    float4 b = *(const float4*)(s + i + 4);
    f16x8 h = {(_Float16)a.x, (_Float16)a.y, (_Float16)a.z, (_Float16)a.w,
               (_Float16)b.x, (_Float16)b.y, (_Float16)b.z, (_Float16)b.w};
    *(f16x8*)(d + i) = h;
}

// ---------------------------------------------------------------- GEMM C = A * B^T
// R11 over R9/R5 (43% MfmaUtil): same data flow, two scheduling defects fixed.
//  (1) Barrier audit: the only REQUIRED syncs are {WAITV; s_barrier} before
//      the first read of a freshly staged chunk (vmcnt is per-wave; barrier
//      publishes other waves' DMA completions). End-of-phase barriers only
//      guarded a WAR that double-buffering already prevents (restages target
//      the other buffer; slot reuse >=5 phases after last read). P2's wait is
//      subsumed by P3's (FIFO: A0(t+1) retires before B0(t+1)). 8 barriers +
//      4 waits -> 3 + 3 per tile; P2 has no sync at all.
//  (2) Full unroll of 15 tiles x 4 phases was ~3000+ instr (~I$ size).
//      #pragma unroll 1 + runtime buffer toggle shrinks the hot loop ~8x.
// Proven-load-bearing pieces kept verbatim: launch-per-round (R8: persistent
// -> 3.2x regression), LDS-staged A+B (R7: B-from-global -> 28% util),
// 3-phase stage->retire depth (R6: deeper neutral), HK-ordered reads,
// LDS-coalesced epilogue, XOR swizzle, XCD-aware decode.

#define WAITV(N) asm volatile("s_waitcnt vmcnt(" #N ")" ::: "memory")
#define BARRIER()                              \
    do {                                       \
        asm volatile("" ::: "memory");         \
        __builtin_amdgcn_s_barrier();          \
        asm volatile("" ::: "memory");         \
    } while (0)

#define ASC(b, c) (Asm + ((b) * 2 + (c)) * 8192)
#define BSC(b, c) (Bsm + ((b) * 2 + (c)) * 8192)

// stage one A-chunk q of K-tile at col k0 into LDS chunk dst (16 KiB).
// phys row = l*64 + rr  <->  logical A row = l*128 + q*64 + rr
#define STAGE_A(dst, q, k0)                                                   \
    do {                                                                      \
        _Pragma("unroll") for (int l = 0; l < 2; ++l)                         \
            async16(Ag + (size_t)(l * 128 + (q) * 64 + rr) * K + (k0) + cc,   \
                    (char*)(dst) + l * 8192 + w * 1024);                      \
    } while (0)

// stage one B-chunk r: phys row = l*64 + rr  <->  logical B col-row =
// (l*2 + wb)*64 + r*32 + (rr&31)
#define STAGE_B(dst, r, k0)                                                   \
    do {                                                                      \
        _Pragma("unroll") for (int l = 0; l < 2; ++l)                         \
            async16(Bg + (size_t)((l * 2 + wb) * 64 + (r) * 32 + (rr & 31)) * K + \
                        (k0) + cc,                                            \
                    (char*)(dst) + l * 8192 + w * 1024);                      \
    } while (0)

// read the 8 A frags (4 mt x 2 kk) of chunk q (buffer b) for this wave
#define READ_A(dstf, b, q)                                                    \
    do {                                                                      \
        _Pragma("unroll") for (int i = 0; i < 4; ++i)                         \
        _Pragma("unroll") for (int x = 0; x < 2; ++x)                         \
            dstf[i][x] = *(const f16x8*)&ASC(b, q)[(wr * 64 + i * 16 + l16) * 64 + \
                                                   (((x * 4 + quad) ^ sw) * 8)]; \
    } while (0)

// read the 4 B frags (2 nt x 2 kk) of chunk r (buffer b) for this wave
#define READ_B(dstf, b, r)                                                    \
    do {                                                                      \
        _Pragma("unroll") for (int i2 = 0; i2 < 2; ++i2)                      \
        _Pragma("unroll") for (int x = 0; x < 2; ++x)                         \
            dstf[i2][x] = *(const f16x8*)&BSC(b, r)[(wc * 32 + i2 * 16 + l16) * 64 + \
                                                    (((x * 4 + quad) ^ sw) * 8)]; \
    } while (0)

// one quadrant: 16 MFMAs into acc[QA*4+i][RB*2+jj]
#define MMA(af, bf, QA, RB)                                                   \
    do {                                                                      \
        __builtin_amdgcn_s_setprio(1);                                        \
        _Pragma("unroll") for (int i = 0; i < 4; ++i)                         \
        _Pragma("unroll") for (int jj = 0; jj < 2; ++jj)                      \
        _Pragma("unroll") for (int x = 0; x < 2; ++x)                         \
            acc[(QA) * 4 + i][(RB) * 2 + jj] =                                \
                __builtin_amdgcn_mfma_f32_16x16x32_f16(                       \
                    af[i][x], bf[jj][x], acc[(QA) * 4 + i][(RB) * 2 + jj], 0, 0, 0); \
        __builtin_amdgcn_s_setprio(0);                                        \
    } while (0)

template <bool QKV>
__global__ __launch_bounds__(512, 2) void gemm_bt(const half_t* __restrict__ A,
                                                  const half_t* __restrict__ Bbase,
                                                  void* __restrict__ Cout,
                                                  const float* __restrict__ theta) {
    constexpr int K  = 1024;
    constexpr int NT = 16;             // K / 64 K-tiles
    constexpr int J  = QKV ? 12 : 4;   // (z, xt) blocks per m-tile
    __shared__ alignas(16) half_t smem[65536];  // 128 KiB
    half_t* Asm = smem;
    half_t* Bsm = smem + 32768;

    const int id    = blockIdx.x;
    const int xcd   = id & 7;
    const int slot  = id >> 3;
    const int ygrp  = slot / J;
    const int j     = slot - ygrp * J;
    const int mtile = ygrp * 8 + xcd;
    const int zsl   = QKV ? (j >> 2) : 0;
    const int xt    = QKV ? (j & 3) : j;

    const int tid  = threadIdx.x;
    const int w    = tid >> 6;
    const int lane = tid & 63;
    const int quad = lane >> 4;
    const int l16  = lane & 15;
    const int sw   = l16 & 7;
    const int wr   = w >> 2, wc = w & 3;  // 2 x 4 waves, each 128x64 of C
    const size_t m0 = (size_t)mtile * 256;
    const int    n0 = xt * 256;

    const half_t* Ag = A + m0 * K;
    const half_t* Bg = Bbase + (size_t)zsl * (size_t)(NE * NE) + (size_t)n0 * K;

    const int rr = tid >> 3;                     // staging row within 64-group
    const int cc = ((tid & 7) ^ (rr & 7)) * 8;   // XOR-pre-swizzled source col
    const int wb = tid >> 8;                     // B col-row bit

    f32x4 acc[8][4];
#pragma unroll
    for (int i = 0; i < 8; ++i)
#pragma unroll
        for (int jj = 0; jj < 4; ++jj) acc[i][jj] = (f32x4){0.f, 0.f, 0.f, 0.f};

    // prologue: 5 chunks issued; retire first two; read first quadrant frags
    STAGE_A(ASC(0, 0), 0, 0);    // A0(0)
    STAGE_B(BSC(0, 0), 0, 0);    // B0(0)
    STAGE_B(BSC(0, 1), 1, 0);    // B1(0)
    STAGE_A(ASC(0, 1), 1, 0);    // A1(0)
    STAGE_A(ASC(1, 0), 0, 64);   // A0(1)
    WAITV(6);                    // retire A0(0), B0(0)
    BARRIER();

    f16x8 aF0[4][2], aF1[4][2], bF0[2][2], bF1[2][2];
    READ_A(aF0, 0, 0);
    READ_B(bF0, 0, 0);
    // invariant before P0(t): outstanding = {B1(t), A1(t), A0(t+1)} = 6 loads

#pragma unroll 1
    for (int t = 0; t < NT - 1; ++t) {
        const int cur = t & 1, nxt = cur ^ 1;
        const int kn = (t + 1) * 64;
        // P0: sync {B1(t)}; stage B0(t+1); MMA q00; read bF1
        WAITV(4);
        BARRIER();
        STAGE_B(BSC(nxt, 0), 0, kn);
        MMA(aF0, bF0, 0, 0);
        READ_B(bF1, cur, 1);
        // P1: sync {A1(t)}; stage B1(t+1); MMA q01; read aF1
        WAITV(4);
        BARRIER();
        STAGE_B(BSC(nxt, 1), 1, kn);
        MMA(aF0, bF1, 0, 1);
        READ_A(aF1, cur, 1);
        // P2: no sync (A0(t+1) retires under P3's wait, FIFO); stage A1(t+1)
        STAGE_A(ASC(nxt, 1), 1, kn);
        MMA(aF1, bF1, 1, 1);
        // P3: sync {A0(t+1), B0(t+1)}; stage A0(t+2); MMA q10; read aF0,bF0
        WAITV(4);
        BARRIER();
        if (t + 2 < NT) STAGE_A(ASC(cur, 0), 0, kn + 64);
        MMA(aF1, bF0, 1, 0);
        READ_A(aF0, nxt, 0);
        READ_B(bF0, nxt, 0);
    }
    // t = NT-1 peeled: outstanding = {B1(15), A1(15)} = 4 loads
    {
        WAITV(2);
        BARRIER();
        MMA(aF0, bF0, 0, 0);
        READ_B(bF1, 1, 1);
        WAITV(0);
        BARRIER();
        MMA(aF0, bF1, 0, 1);
        READ_A(aF1, 1, 1);
        MMA(aF1, bF1, 1, 1);
        MMA(aF1, bF0, 1, 0);
    }
    __syncthreads();  // LDS now dead -> reuse for coalesced C staging

    // C/D layout: col = lane&15, row = quad*4 + reg  [m89]
    if (QKV) {
        // stage cos(acc+theta) as f16 [256][256] in LDS with bank-XOR
        half_t* Cl = smem;
#pragma unroll
        for (int nt = 0; nt < 4; ++nt) {
            const int col = wc * 64 + nt * 16 + l16;
            const float th = theta[col & 63];
#pragma unroll
            for (int mt = 0; mt < 8; ++mt) {
                const int rowb = wr * 128 + mt * 16 + quad * 4;
#pragma unroll
                for (int r = 0; r < 4; ++r) {
                    const int row = rowb + r;
                    Cl[row * 256 + (col ^ (((row >> 2) & 3) << 4))] =
                        (half_t)__cosf(acc[mt][nt][r] + th);
                }
            }
        }
        __syncthreads();
        half_t* Cg = (half_t*)Cout + (size_t)zsl * ((size_t)NTOK * NE);
#pragma unroll
        for (int it = 0; it < 16; ++it) {
            const int row = it * 16 + (tid >> 5);
            const int seg = tid & 31;
            f16x8 vv = *(const f16x8*)&Cl[row * 256 +
                                          ((seg * 8) ^ (((row >> 2) & 3) << 4))];
            *(f16x8*)&Cg[(m0 + row) * NE + n0 + seg * 8] = vv;  // 512 B / 32 lanes
        }
    } else {
        // f32 out: two 128-row sweeps through LDS [128][256] f32
        float* ClF = (float*)smem;
        float* Cg  = (float*)Cout;
#pragma unroll
        for (int s = 0; s < 2; ++s) {
            if (wr == s) {
#pragma unroll
                for (int nt = 0; nt < 4; ++nt) {
                    const int col = wc * 64 + nt * 16 + l16;
#pragma unroll
                    for (int mt = 0; mt < 8; ++mt) {
                        const int rowb = mt * 16 + quad * 4;
#pragma unroll
                        for (int r = 0; r < 4; ++r) {
                            const int row = rowb + r;
                            ClF[row * 256 + (col ^ (((row >> 2) & 1) << 4))] =
                                acc[mt][nt][r];
                        }
                    }
                }
            }
            __syncthreads();
#pragma unroll
            for (int it = 0; it < 16; ++it) {
                const int row = it * 8 + (tid >> 6);
                const int seg = tid & 63;
                f32x4 vv = *(const f32x4*)&ClF[row * 256 +
                                               ((seg * 4) ^ (((row >> 2) & 1) << 4))];
                *(f32x4*)&Cg[(m0 + s * 128 + row) * NE + n0 + seg * 4] = vv;
            }
            __syncthreads();
        }
    }
}

// ---------------------------------------------------------------- MFMA attention
// R11 = R9 attn verbatim (best measured). 8 tokens/block, one wave = one
// token. Scores S[16x16] = q.k^T over d=64 via two 16x16x32 MFMAs; q/k frags
// straight from global in A/B layout [m|n = lane&15][k = quad*8+j]. Softmax
// rows reduced with 16-wide shuffle butterflies. PV via four 16x16x16 MFMAs:
// P and v^T round-trip LDS with stride 20 (conflict-free).
__global__ __launch_bounds__(512) void attn_kernel(const half_t* __restrict__ q,
                                                   const half_t* __restrict__ k,
                                                   const half_t* __restrict__ v,
                                                   half_t* __restrict__ out) {
    __shared__ half_t vT[8][64][20];  // [wave][d][head j], pad->20
    __shared__ half_t Pl[8][16][20];  // [wave][i][j], pad->20
    const int tid  = threadIdx.x;
    const int w    = tid >> 6;
    const int lane = tid & 63;
    const int quad = lane >> 4;
    const int l16  = lane & 15;
    const size_t base = ((size_t)blockIdx.x * 8 + w) * 1024;

    // stage v transposed: lane covers head h = lane>>2, d-chunk (lane&3)*16
    {
        const int h = lane >> 2, d0 = (lane & 3) * 16;
        f16x8 va = *(const f16x8*)(v + base + h * 64 + d0);
        f16x8 vb = *(const f16x8*)(v + base + h * 64 + d0 + 8);
#pragma unroll
        for (int z = 0; z < 8; ++z) {
            vT[w][d0 + z][h]     = va[z];
            vT[w][d0 + 8 + z][h] = vb[z];
        }
    }

    // scores: frags straight from global (no LDS)
    f16x8 aq0 = *(const f16x8*)(q + base + l16 * 64 + quad * 8);
    f16x8 aq1 = *(const f16x8*)(q + base + l16 * 64 + 32 + quad * 8);
    f16x8 bk0 = *(const f16x8*)(k + base + l16 * 64 + quad * 8);
    f16x8 bk1 = *(const f16x8*)(k + base + l16 * 64 + 32 + quad * 8);
    f32x4 S = __builtin_amdgcn_mfma_f32_16x16x32_f16(aq0, bk0, (f32x4){0.f,0.f,0.f,0.f}, 0, 0, 0);
    S = __builtin_amdgcn_mfma_f32_16x16x32_f16(aq1, bk1, S, 0, 0, 0);

    // softmax over cols (l16) per row (quad*4+r); write P f16 to LDS
#pragma unroll
    for (int r = 0; r < 4; ++r) {
        float s = S[r] * 0.125f;  // 1/sqrt(64)
        float mx = s;
#pragma unroll
        for (int o = 8; o; o >>= 1) mx = fmaxf(mx, __shfl_xor(mx, o));
        float e = __expf(s - mx);
        float sum = e;
#pragma unroll
        for (int o = 8; o; o >>= 1) sum += __shfl_xor(sum, o);
        Pl[w][quad * 4 + r][l16] = (half_t)(e / sum);
    }
    __syncthreads();  // vT + Pl visible across lanes

    // PV: A = P [m=i][k=j], B = v^T [k=j][n=d], 4 d-chunks of 16
    f16x4 ap = *(const f16x4*)&Pl[w][l16][quad * 4];
#pragma unroll
    for (int c = 0; c < 4; ++c) {
        f16x4 bv = *(const f16x4*)&vT[w][c * 16 + l16][quad * 4];
        f32x4 O = __builtin_amdgcn_mfma_f32_16x16x16f16(ap, bv, (f32x4){0.f,0.f,0.f,0.f}, 0, 0, 0);
#pragma unroll
        for (int r = 0; r < 4; ++r)
            out[base + (quad * 4 + r) * 64 + c * 16 + l16] = (half_t)O[r];
    }
}

// ---------------------------------------------------------------- launch
extern "C" void kernel_launch(void* const* d_in, const int* in_sizes, int n_in,
                              void* d_out, int out_size, void* d_ws, size_t ws_size,
                              hipStream_t stream) {
    // setup_inputs order: x, Wk, Wq, Wv, Wo, theta
    const float* x     = (const float*)d_in[0];
    const float* Wk    = (const float*)d_in[1];
    const float* Wq    = (const float*)d_in[2];
    const float* Wv    = (const float*)d_in[3];
    const float* Wo    = (const float*)d_in[4];
    const float* theta = (const float*)d_in[5];

    char* ws = (char*)d_ws;
    half_t* xh  = (half_t*)ws;                           // 64 MB (reused for attn_out)
    half_t* wh  = (half_t*)(ws + (size_t)(64 << 20));    // 8 MB: Wq,Wk,Wv,Wo f16
    half_t* qkv = (half_t*)(ws + (size_t)(72 << 20));    // 192 MB: q_q,k_q,v_q f16

    // all conversions in one launch: x (16384 blocks) + 4 weights (512 each)
    cvt_all<<<16384 + 4 * 512, 256, 0, stream>>>(x, Wq, Wk, Wv, Wo, xh, wh);

    // q,k,v projections + cos(.+theta): 8 xcd * 16 ygrp * 12 (z,x); 256x256 tiles
    gemm_bt<true><<<1536, 512, 0, stream>>>(xh, wh, qkv, theta);

    // per-token attention over heads (8 tokens/block)
    attn_kernel<<<NTOK / 8, 512, 0, stream>>>(qkv, qkv + (size_t)NTOK * NE,
                                              qkv + 2 * (size_t)NTOK * NE, xh);

    // out = attn_out @ Wo^T: 8 xcd * 16 ygrp * 4 xt
    gemm_bt<false><<<512, 512, 0, stream>>>(xh, wh + 3 * NE * NE, d_out, nullptr);
}